// Round 4
// baseline (704.237 us; speedup 1.0000x reference)
//
#include <hip/hip_runtime.h>
#include <hip/hip_bf16.h>

#define D 64   // D_IN == D_OUT == 64

// ---------------------------------------------------------------------------
// k1: packed[i]=0 (cnt=0, deg_fixed=0), counter=0
__global__ __launch_bounds__(256) void k_init(unsigned long long* __restrict__ packed,
                                              int* __restrict__ counter, int n) {
    int i = blockIdx.x * 256 + threadIdx.x;
    if (i < n) packed[i] = 0ULL;
    if (i == 0) *counter = 0;
}

// k2: ONE 64-bit atomic per edge. high 20 bits = edge count, low 44 bits =
// fixed-point (2^-32) sum of ew. Returned old value gives this edge's rank
// within its row for free -> atomic-free placement later.
__global__ __launch_bounds__(256) void k_count(const int* __restrict__ rowi,
                                               const float* __restrict__ ew,
                                               unsigned long long* __restrict__ packed,
                                               int* __restrict__ rank, int nE) {
    int e = blockIdx.x * 256 + threadIdx.x;
    if (e < nE) {
        unsigned long long fx = (unsigned long long)((double)ew[e] * 4294967296.0);
        unsigned long long old = atomicAdd(&packed[rowi[e]], (1ULL << 44) | fx);
        rank[e] = (int)(old >> 44);
    }
}

// k3: unpack deg (+1.0 self-loop), dis=rsqrt(deg); CSR segment assignment via
// wave-scan -> one atomic per wave.
__global__ __launch_bounds__(256) void k_dis_seg(const unsigned long long* __restrict__ packed,
                                                 float* __restrict__ deg,
                                                 float* __restrict__ dis,
                                                 int* __restrict__ cnt,
                                                 int* __restrict__ start,
                                                 int* __restrict__ counter, int n) {
    int i = blockIdx.x * 256 + threadIdx.x;
    int lane = threadIdx.x & 63;
    unsigned long long p = (i < n) ? packed[i] : 0ULL;
    int c = (int)(p >> 44);
    float dg = (float)(1.0 + (double)(p & ((1ULL << 44) - 1)) * (1.0 / 4294967296.0));
    if (i < n) {
        deg[i] = dg;
        dis[i] = rsqrtf(dg);
        cnt[i] = c;
    }
    int incl = c;
#pragma unroll
    for (int o = 1; o < 64; o <<= 1) {
        int t = __shfl_up(incl, o, 64);
        if (lane >= o) incl += t;
    }
    int total = __shfl(incl, 63, 64);
    int base = 0;
    if (lane == 0) base = atomicAdd(counter, total);
    base = __shfl(base, 0, 64);
    if (i < n) start[i] = base + incl - c;
}

// k4: atomic-free placement: p = start[row] + rank[e]; pack (col, ew*dis[col]).
__global__ __launch_bounds__(256) void k_place(const int* __restrict__ rowi,
                                               const int* __restrict__ coli,
                                               const float* __restrict__ ew,
                                               const float* __restrict__ dis,
                                               const int* __restrict__ start,
                                               const int* __restrict__ rank,
                                               int2* __restrict__ scw, int nE) {
    int e = blockIdx.x * 256 + threadIdx.x;
    if (e < nE) {
        int c = coli[e];
        int p = start[rowi[e]] + rank[e];
        scw[p] = make_int2(c, __float_as_int(ew[e] * dis[c]));
    }
}

// k5: gather-aggregate, 16 lanes/node, float4 channel-slice per lane.
// The 16 lanes batch-load 16 edge descriptors in one instruction, then an
// unrolled shuffle loop issues up to 16 INDEPENDENT x-row loads (deep ILP).
__global__ __launch_bounds__(256) void k_gather(const float* __restrict__ x,
                                                const float* __restrict__ deg,
                                                const float* __restrict__ dis,
                                                const int* __restrict__ start,
                                                const int* __restrict__ cnt,
                                                const int2* __restrict__ scw,
                                                float* __restrict__ agg, int n) {
    int g = blockIdx.x * 256 + threadIdx.x;
    int i = g >> 4;
    if (i >= n) return;
    int j = g & 15;

    const float4* x4 = (const float4*)x;
    float4 acc = make_float4(0.f, 0.f, 0.f, 0.f);

    int s = start[i];
    int e_end = s + cnt[i];
    for (int e = s; e < e_end; e += 16) {
        int idx = e + j;                       // lane j prefetches edge e+j
        int2 v = make_int2(0, 0);
        if (idx < e_end) v = scw[idx];
        int m = e_end - e; if (m > 16) m = 16; // uniform within 16-lane group
#pragma unroll
        for (int t = 0; t < 16; ++t) {
            if (t < m) {
                int col = __shfl(v.x, t, 16);
                float w = __int_as_float(__shfl(v.y, t, 16));
                float4 xv = x4[col * 16 + j];
                acc.x += w * xv.x; acc.y += w * xv.y;
                acc.z += w * xv.z; acc.w += w * xv.w;
            }
        }
    }

    float di  = dis[i];
    float inv = 1.0f / deg[i];                 // self-loop: dis[i]*1*dis[i]
    float4 xs = x4[i * 16 + j];
    float4 o;
    o.x = xs.x * inv + di * acc.x;
    o.y = xs.y * inv + di * acc.y;
    o.z = xs.z * inv + di * acc.z;
    o.w = xs.w * inv + di * acc.w;
    ((float4*)agg)[i * 16 + j] = o;
}

// k6: out = agg @ W^T + bias.
// NEW STRUCTURE: A never touches LDS. 16 lanes per row-group; lane j holds
// k=4j..4j+3 of each row in registers AND owns out-channels 4j..4j+3.
// A-broadcast via __shfl(width=16); only W lives in LDS as Bs[k][o] (pad 68:
// b128 reads hit banks 4j..4j+3 -> 2-way, free; identical addrs across the
// wave's 4 groups -> broadcast). M=8 rows/group amortizes LDS to 2KB/row.
// VGPR ~110 (vs 252 before) -> 4 waves/SIMD. In-place safe: each row is
// read and written by exactly one group.
#define GM 8   // rows per 16-lane group
__global__ __launch_bounds__(256) void gcn_gemm(const float* __restrict__ agg,
                                                const float* __restrict__ W,
                                                const float* __restrict__ bias,
                                                float* __restrict__ out, int n) {
    __shared__ float Bs[D][68];   // Bs[k][o] = W[o][k]
    int tid = threadIdx.x;

    // stage W (one-time; scatter-transpose, conflicts negligible)
    const float4* W4 = (const float4*)W;
#pragma unroll
    for (int v = 0; v < 4; ++v) {
        int idx = tid + v * 256;          // 0..1023
        int o  = idx >> 4;                // 0..63
        int k0 = (idx & 15) * 4;
        float4 wv = W4[idx];
        Bs[k0 + 0][o] = wv.x; Bs[k0 + 1][o] = wv.y;
        Bs[k0 + 2][o] = wv.z; Bs[k0 + 3][o] = wv.w;
    }
    __syncthreads();

    int j   = tid & 15;                   // lane in group: k-slice & out-slice
    int grp = tid >> 4;                   // 0..15
    int r0  = (blockIdx.x * 16 + grp) * GM;

    const float4* A4 = (const float4*)agg;
    float4 rv[GM];
#pragma unroll
    for (int m = 0; m < GM; ++m) {
        rv[m] = make_float4(0.f, 0.f, 0.f, 0.f);
        if (r0 + m < n) rv[m] = A4[(r0 + m) * 16 + j];
    }

    float4 bv = ((const float4*)bias)[j];
    float4 acc[GM];
#pragma unroll
    for (int m = 0; m < GM; ++m) acc[m] = bv;

#pragma unroll
    for (int t = 0; t < 16; ++t) {
        float4 b0 = *(const float4*)&Bs[4 * t + 0][4 * j];
        float4 b1 = *(const float4*)&Bs[4 * t + 1][4 * j];
        float4 b2 = *(const float4*)&Bs[4 * t + 2][4 * j];
        float4 b3 = *(const float4*)&Bs[4 * t + 3][4 * j];
#pragma unroll
        for (int m = 0; m < GM; ++m) {
            float ax = __shfl(rv[m].x, t, 16);
            float ay = __shfl(rv[m].y, t, 16);
            float az = __shfl(rv[m].z, t, 16);
            float aw = __shfl(rv[m].w, t, 16);
            acc[m].x += ax * b0.x + ay * b1.x + az * b2.x + aw * b3.x;
            acc[m].y += ax * b0.y + ay * b1.y + az * b2.y + aw * b3.y;
            acc[m].z += ax * b0.z + ay * b1.z + az * b2.z + aw * b3.z;
            acc[m].w += ax * b0.w + ay * b1.w + az * b2.w + aw * b3.w;
        }
    }

    float4* out4 = (float4*)out;
#pragma unroll
    for (int m = 0; m < GM; ++m) {
        if (r0 + m < n) out4[(r0 + m) * 16 + j] = acc[m];
    }
}

extern "C" void kernel_launch(void* const* d_in, const int* in_sizes, int n_in,
                              void* d_out, int out_size, void* d_ws, size_t ws_size,
                              hipStream_t stream) {
    const float* x    = (const float*)d_in[0];
    const int*   ei   = (const int*)d_in[1];   // [2*E] flat: rows then cols
    const float* ew   = (const float*)d_in[2];
    const float* W    = (const float*)d_in[3];
    const float* bias = (const float*)d_in[4];
    float* out = (float*)d_out;

    int n  = in_sizes[0] / D;   // 100000
    int nE = in_sizes[2];       // 1000000
    const int* rowi = ei;
    const int* coli = ei + nE;

    // workspace layout (widest alignment first): ~14.4 MB
    char* w = (char*)d_ws;
    unsigned long long* packed = (unsigned long long*)w; w += (size_t)n * 8;
    int2*  scw     = (int2*)w;              w += (size_t)nE * sizeof(int2);
    int*   rank    = (int*)w;               w += (size_t)nE * sizeof(int);
    float* deg     = (float*)w;             w += (size_t)n * sizeof(float);
    float* dis     = (float*)w;             w += (size_t)n * sizeof(float);
    int*   cnt     = (int*)w;               w += (size_t)n * sizeof(int);
    int*   startA  = (int*)w;               w += (size_t)n * sizeof(int);
    int*   counter = (int*)w;

    int gn = (n + 255) / 256;
    int gE = (nE + 255) / 256;

    k_init   <<<gn, 256, 0, stream>>>(packed, counter, n);
    k_count  <<<gE, 256, 0, stream>>>(rowi, ew, packed, rank, nE);
    k_dis_seg<<<gn, 256, 0, stream>>>(packed, deg, dis, cnt, startA, counter, n);
    k_place  <<<gE, 256, 0, stream>>>(rowi, coli, ew, dis, startA, rank, scw, nE);
    k_gather <<<(n * 16 + 255) / 256, 256, 0, stream>>>(x, deg, dis, startA, cnt, scw, out, n);
    int ngrp = (n + GM - 1) / GM;                       // 12500 row-groups
    gcn_gemm <<<(ngrp + 15) / 16, 256, 0, stream>>>(out, W, bias, out, n);
}

// Round 5
// 227.675 us; speedup vs baseline: 3.0932x; 3.0932x over previous
//
#include <hip/hip_runtime.h>
#include <hip/hip_bf16.h>

#define D 64   // D_IN == D_OUT == 64

// ---------------------------------------------------------------------------
// k1: packed[i]=0 (cnt=0, deg_fixed=0), counter=0
__global__ __launch_bounds__(256) void k_init(unsigned long long* __restrict__ packed,
                                              int* __restrict__ counter, int n) {
    int i = blockIdx.x * 256 + threadIdx.x;
    if (i < n) packed[i] = 0ULL;
    if (i == 0) *counter = 0;
}

// k2: ONE 64-bit atomic per edge. high 20 bits = edge count, low 44 bits =
// fixed-point (2^-32) sum of ew. Returned old value gives this edge's rank
// within its row for free -> atomic-free placement later.
__global__ __launch_bounds__(256) void k_count(const int* __restrict__ rowi,
                                               const float* __restrict__ ew,
                                               unsigned long long* __restrict__ packed,
                                               int* __restrict__ rank, int nE) {
    int e = blockIdx.x * 256 + threadIdx.x;
    if (e < nE) {
        unsigned long long fx = (unsigned long long)((double)ew[e] * 4294967296.0);
        unsigned long long old = atomicAdd(&packed[rowi[e]], (1ULL << 44) | fx);
        rank[e] = (int)(old >> 44);
    }
}

// k3: unpack deg (+1.0 self-loop), dis=rsqrt(deg); CSR segment assignment via
// wave-scan -> one atomic per wave.
__global__ __launch_bounds__(256) void k_dis_seg(const unsigned long long* __restrict__ packed,
                                                 float* __restrict__ deg,
                                                 float* __restrict__ dis,
                                                 int* __restrict__ cnt,
                                                 int* __restrict__ start,
                                                 int* __restrict__ counter, int n) {
    int i = blockIdx.x * 256 + threadIdx.x;
    int lane = threadIdx.x & 63;
    unsigned long long p = (i < n) ? packed[i] : 0ULL;
    int c = (int)(p >> 44);
    float dg = (float)(1.0 + (double)(p & ((1ULL << 44) - 1)) * (1.0 / 4294967296.0));
    if (i < n) {
        deg[i] = dg;
        dis[i] = rsqrtf(dg);
        cnt[i] = c;
    }
    int incl = c;
#pragma unroll
    for (int o = 1; o < 64; o <<= 1) {
        int t = __shfl_up(incl, o, 64);
        if (lane >= o) incl += t;
    }
    int total = __shfl(incl, 63, 64);
    int base = 0;
    if (lane == 0) base = atomicAdd(counter, total);
    base = __shfl(base, 0, 64);
    if (i < n) start[i] = base + incl - c;
}

// k4: atomic-free placement: p = start[row] + rank[e]; pack (col, ew*dis[col]).
__global__ __launch_bounds__(256) void k_place(const int* __restrict__ rowi,
                                               const int* __restrict__ coli,
                                               const float* __restrict__ ew,
                                               const float* __restrict__ dis,
                                               const int* __restrict__ start,
                                               const int* __restrict__ rank,
                                               int2* __restrict__ scw, int nE) {
    int e = blockIdx.x * 256 + threadIdx.x;
    if (e < nE) {
        int c = coli[e];
        int p = start[rowi[e]] + rank[e];
        scw[p] = make_int2(c, __float_as_int(ew[e] * dis[c]));
    }
}

// k5: gather-aggregate, 16 lanes/node, float4 channel-slice per lane.
__global__ __launch_bounds__(256) void k_gather(const float* __restrict__ x,
                                                const float* __restrict__ deg,
                                                const float* __restrict__ dis,
                                                const int* __restrict__ start,
                                                const int* __restrict__ cnt,
                                                const int2* __restrict__ scw,
                                                float* __restrict__ agg, int n) {
    int g = blockIdx.x * 256 + threadIdx.x;
    int i = g >> 4;
    if (i >= n) return;
    int j = g & 15;

    const float4* x4 = (const float4*)x;
    float4 acc = make_float4(0.f, 0.f, 0.f, 0.f);

    int s = start[i];
    int e_end = s + cnt[i];
    for (int e = s; e < e_end; e += 16) {
        int idx = e + j;                       // lane j prefetches edge e+j
        int2 v = make_int2(0, 0);
        if (idx < e_end) v = scw[idx];
        int m = e_end - e; if (m > 16) m = 16; // uniform within 16-lane group
#pragma unroll
        for (int t = 0; t < 16; ++t) {
            if (t < m) {
                int col = __shfl(v.x, t, 16);
                float w = __int_as_float(__shfl(v.y, t, 16));
                float4 xv = x4[col * 16 + j];
                acc.x += w * xv.x; acc.y += w * xv.y;
                acc.z += w * xv.z; acc.w += w * xv.w;
            }
        }
    }

    float di  = dis[i];
    float inv = 1.0f / deg[i];                 // self-loop: dis[i]*1*dis[i]
    float4 xs = x4[i * 16 + j];
    float4 o;
    o.x = xs.x * inv + di * acc.x;
    o.y = xs.y * inv + di * acc.y;
    o.z = xs.z * inv + di * acc.z;
    o.w = xs.w * inv + di * acc.w;
    ((float4*)agg)[i * 16 + j] = o;
}

// k6: out = agg @ W^T + bias. 64-row tile, 4x4 register tile per thread.
// Swizzled LDS layouts (no padding) keep every LDS op at its bandwidth floor:
//   Ast (row-major): row r, k-chunk kc stored at float4-slot (kc + (r>>2))&15.
//     Staging = pure b128 writes; compute reads hit 2 addrs/bank-quad (free).
//   Bs (k-major, transposed W): row k, o-chunk g stored at slot (g + k)&15.
//     Compute b128 reads at floor; staging is 16 scalar stores (~2x floor, tiny).
// launch_bounds(256,4) caps VGPR at 128 (acc 16 + frags 32 -> fits easily);
// k-loop chunked by 4, unroll 4 -> no register blowup (round-4 lesson).
// In-place safe: block stages its 64 rows into LDS before overwriting them.
__global__ __launch_bounds__(256, 4) void gcn_gemm(const float* __restrict__ agg,
                                                   const float* __restrict__ W,
                                                   const float* __restrict__ bias,
                                                   float* __restrict__ out, int n) {
    __shared__ float Ast[D * D];   // 16 KB, float4-slot addressed
    __shared__ float Bs[D * D];    // 16 KB
    float4* Ast4 = (float4*)Ast;
    int tid = threadIdx.x;
    int r0 = blockIdx.x * 64;

    const float4* W4 = (const float4*)W;
    const float4* A4 = (const float4*)agg;
#pragma unroll
    for (int v = 0; v < 4; ++v) {
        int idx = tid + v * 256;          // 0..1023
        int a  = idx >> 4;                // row (A) / out-ch o (W), 0..63
        int kc = idx & 15;                // k-chunk
        // A tile: b128 write, swizzled slot
        int ra = r0 + a;
        float4 av = make_float4(0.f, 0.f, 0.f, 0.f);
        if (ra < n) av = A4[ra * 16 + kc];
        Ast4[a * 16 + ((kc + (a >> 2)) & 15)] = av;
        // B tile: transpose via 4 scalar writes, swizzled slot (g+k)&15
        float4 wv = W4[idx];              // W[o][4kc..4kc+3], o = a
        int g = a >> 2, oo = a & 3;
        {
            int k = 4 * kc + 0; Bs[k * 64 + 4 * ((g + k) & 15) + oo] = wv.x;
        }
        {
            int k = 4 * kc + 1; Bs[k * 64 + 4 * ((g + k) & 15) + oo] = wv.y;
        }
        {
            int k = 4 * kc + 2; Bs[k * 64 + 4 * ((g + k) & 15) + oo] = wv.z;
        }
        {
            int k = 4 * kc + 3; Bs[k * 64 + 4 * ((g + k) & 15) + oo] = wv.w;
        }
    }
    __syncthreads();

    int ty = tid >> 4;   // row group: rows 4ty..4ty+3
    int tx = tid & 15;   // out-ch group: o = 4tx..4tx+3
    float acc[4][4];
#pragma unroll
    for (int m = 0; m < 4; ++m)
#pragma unroll
        for (int q = 0; q < 4; ++q) acc[m][q] = 0.f;

#pragma unroll 4
    for (int kc = 0; kc < 16; ++kc) {
        float4 a4[4], b4[4];
#pragma unroll
        for (int m = 0; m < 4; ++m)
            a4[m] = Ast4[(4 * ty + m) * 16 + ((kc + ty) & 15)];
#pragma unroll
        for (int i = 0; i < 4; ++i) {
            int k = 4 * kc + i;
            b4[i] = *(const float4*)&Bs[k * 64 + 4 * ((tx + k) & 15)];
        }
#pragma unroll
        for (int m = 0; m < 4; ++m) {
            acc[m][0] += a4[m].x * b4[0].x + a4[m].y * b4[1].x + a4[m].z * b4[2].x + a4[m].w * b4[3].x;
            acc[m][1] += a4[m].x * b4[0].y + a4[m].y * b4[1].y + a4[m].z * b4[2].y + a4[m].w * b4[3].y;
            acc[m][2] += a4[m].x * b4[0].z + a4[m].y * b4[1].z + a4[m].z * b4[2].z + a4[m].w * b4[3].z;
            acc[m][3] += a4[m].x * b4[0].w + a4[m].y * b4[1].w + a4[m].z * b4[2].w + a4[m].w * b4[3].w;
        }
    }

    float4 bv = ((const float4*)bias)[tx];
    float4* out4 = (float4*)out;
#pragma unroll
    for (int m = 0; m < 4; ++m) {
        int r = r0 + 4 * ty + m;
        if (r < n) {
            float4 o;
            o.x = acc[m][0] + bv.x; o.y = acc[m][1] + bv.y;
            o.z = acc[m][2] + bv.z; o.w = acc[m][3] + bv.w;
            out4[r * 16 + tx] = o;
        }
    }
}

extern "C" void kernel_launch(void* const* d_in, const int* in_sizes, int n_in,
                              void* d_out, int out_size, void* d_ws, size_t ws_size,
                              hipStream_t stream) {
    const float* x    = (const float*)d_in[0];
    const int*   ei   = (const int*)d_in[1];   // [2*E] flat: rows then cols
    const float* ew   = (const float*)d_in[2];
    const float* W    = (const float*)d_in[3];
    const float* bias = (const float*)d_in[4];
    float* out = (float*)d_out;

    int n  = in_sizes[0] / D;   // 100000
    int nE = in_sizes[2];       // 1000000
    const int* rowi = ei;
    const int* coli = ei + nE;

    // workspace layout (widest alignment first): ~14.4 MB
    char* w = (char*)d_ws;
    unsigned long long* packed = (unsigned long long*)w; w += (size_t)n * 8;
    int2*  scw     = (int2*)w;              w += (size_t)nE * sizeof(int2);
    int*   rank    = (int*)w;               w += (size_t)nE * sizeof(int);
    float* deg     = (float*)w;             w += (size_t)n * sizeof(float);
    float* dis     = (float*)w;             w += (size_t)n * sizeof(float);
    int*   cnt     = (int*)w;               w += (size_t)n * sizeof(int);
    int*   startA  = (int*)w;               w += (size_t)n * sizeof(int);
    int*   counter = (int*)w;

    int gn = (n + 255) / 256;
    int gE = (nE + 255) / 256;

    k_init   <<<gn, 256, 0, stream>>>(packed, counter, n);
    k_count  <<<gE, 256, 0, stream>>>(rowi, ew, packed, rank, nE);
    k_dis_seg<<<gn, 256, 0, stream>>>(packed, deg, dis, cnt, startA, counter, n);
    k_place  <<<gE, 256, 0, stream>>>(rowi, coli, ew, dis, startA, rank, scw, nE);
    k_gather <<<(n * 16 + 255) / 256, 256, 0, stream>>>(x, deg, dis, startA, cnt, scw, out, n);
    gcn_gemm <<<(n + 63) / 64, 256, 0, stream>>>(out, W, bias, out, n);
}